// Round 1
// baseline (402.543 us; speedup 1.0000x reference)
//
#include <hip/hip_runtime.h>
#include <hip/hip_bf16.h>

typedef unsigned short u16;
typedef unsigned int   u32;
typedef __attribute__((ext_vector_type(8))) short bf16x8;
typedef __attribute__((ext_vector_type(4))) float f32x4;

#define MFMA16(a,b,c) __builtin_amdgcn_mfma_f32_16x16x32_bf16((a),(b),(c),0,0,0)

#define GLD16(gp, lp) __builtin_amdgcn_global_load_lds( \
    (const __attribute__((address_space(1))) void*)(gp), \
    (__attribute__((address_space(3))) void*)(lp), 16, 0, 0)

// ---------------------------------------------------------------- cast f32->bf16
__global__ __launch_bounds__(256) void cast_f32_bf16(const float* __restrict__ src,
                                                     u16* __restrict__ dst, int n4) {
  int i = blockIdx.x * 256 + threadIdx.x;
  if (i >= n4) return;
  float4 v = reinterpret_cast<const float4*>(src)[i];
  __hip_bfloat16 h0 = __float2bfloat16(v.x);
  __hip_bfloat16 h1 = __float2bfloat16(v.y);
  __hip_bfloat16 h2 = __float2bfloat16(v.z);
  __hip_bfloat16 h3 = __float2bfloat16(v.w);
  u32 lo = (u32)(*(u16*)&h0) | ((u32)(*(u16*)&h1) << 16);
  u32 hi = (u32)(*(u16*)&h2) | ((u32)(*(u16*)&h3) << 16);
  uint2 pk; pk.x = lo; pk.y = hi;
  reinterpret_cast<uint2*>(dst)[i] = pk;
}

// ---------------------------------------------------------------- GEMM C = A * B^T
// A [M][K] bf16 row-major, B [N][K] bf16 row-major, C [M][N].
__device__ inline void cstore(u16* C, size_t i, float v) {
  __hip_bfloat16 h = __float2bfloat16(v); C[i] = *(u16*)&h;
}
__device__ inline void cstore(float* C, size_t i, float v) { C[i] = v; }

template<typename OutT>
__global__ __launch_bounds__(256) void gemm_bt(const u16* __restrict__ A,
                                               const u16* __restrict__ B,
                                               OutT* __restrict__ C,
                                               int M, int N, int K) {
  __shared__ u16 As[128 * 32];
  __shared__ u16 Bs[128 * 32];
  const int t = threadIdx.x;
  const int lane = t & 63, wid = t >> 6;
  const int l15 = lane & 15, l4 = lane >> 4;
  const int wr = wid >> 1, wc = wid & 1;
  const int m0 = blockIdx.y * 128, n0 = blockIdx.x * 128;

  const int srow = t >> 2, scol = (t & 3) << 3;       // staging: byte = t*16, linear
  const u16* Ag = A + (size_t)(m0 + srow) * K + scol;
  const u16* Bg = B + (size_t)(n0 + srow) * K + scol;
  u16* As_d  = &As[srow * 32 + scol];
  u16* As_d2 = &As[(srow + 64) * 32 + scol];
  u16* Bs_d  = &Bs[srow * 32 + scol];
  u16* Bs_d2 = &Bs[(srow + 64) * 32 + scol];

  const int fra = wr * 64 + l15;
  const int frb = wc * 64 + l15;
  const int fk  = l4 << 3;

  f32x4 acc[4][4] = {};
  for (int k0 = 0; k0 < K; k0 += 32) {
    __syncthreads();
    GLD16(Ag + k0,                 As_d);
    GLD16(Ag + (size_t)64*K + k0,  As_d2);
    GLD16(Bg + k0,                 Bs_d);
    GLD16(Bg + (size_t)64*K + k0,  Bs_d2);
    __syncthreads();
    bf16x8 af[4], bfr[4];
#pragma unroll
    for (int m = 0; m < 4; ++m) af[m]  = *(const bf16x8*)&As[(fra + m*16)*32 + fk];
#pragma unroll
    for (int n = 0; n < 4; ++n) bfr[n] = *(const bf16x8*)&Bs[(frb + n*16)*32 + fk];
#pragma unroll
    for (int m = 0; m < 4; ++m)
#pragma unroll
      for (int n = 0; n < 4; ++n)
        acc[m][n] = MFMA16(af[m], bfr[n], acc[m][n]);
  }
  const int crow = m0 + wr * 64 + (l4 << 2);
  const int ccol = n0 + wc * 64 + l15;
#pragma unroll
  for (int m = 0; m < 4; ++m)
#pragma unroll
    for (int n = 0; n < 4; ++n)
#pragma unroll
      for (int r = 0; r < 4; ++r)
        cstore(C, (size_t)(crow + m*16 + r) * N + (ccol + n*16), acc[m][n][r]);
}

// ---------------------------------------------------------------- RMSNorm + RoPE
// qkv [4096][3072] bf16; q heads cols h*128 (h<16); k heads cols 2048+h*128 (h<4).
__global__ __launch_bounds__(256) void rmsrope_kernel(u16* __restrict__ qkv) {
  const int t = threadIdx.x;
  const int lane = t & 63;
  const int gw = blockIdx.x * 4 + (t >> 6);           // 0..81919
  const int row = gw / 20;
  const int hd = gw - row * 20;
  const int col = (hd < 16) ? hd * 128 : 2048 + (hd - 16) * 128;
  const size_t base = (size_t)row * 3072 + col;
  float x1 = __bfloat162float(*(const __hip_bfloat16*)&qkv[base + lane]);
  float x2 = __bfloat162float(*(const __hip_bfloat16*)&qkv[base + 64 + lane]);
  float ss = x1 * x1 + x2 * x2;
#pragma unroll
  for (int off = 32; off >= 1; off >>= 1) ss += __shfl_xor(ss, off, 64);
  const float sc = rsqrtf(ss * (1.0f / 128.0f) + 1e-6f);
  const int pos = row & 2047;
  const float inv_freq = exp2f(-(float)lane * (13.287712379549449f / 64.0f));
  float sn, cs;
  sincosf((float)pos * inv_freq, &sn, &cs);
  const float a = x1 * sc, b2 = x2 * sc;
  __hip_bfloat16 o1 = __float2bfloat16(a * cs - b2 * sn);
  __hip_bfloat16 o2 = __float2bfloat16(a * sn + b2 * cs);
  qkv[base + lane] = *(u16*)&o1;
  qkv[base + 64 + lane] = *(u16*)&o2;
}

// ---------------------------------------------------------------- flash attention
// Causal GQA. grid (32 qtiles, 16 heads, 2 batch), 256 thr. 64 q-rows/block.
__global__ __launch_bounds__(256) void attn_kernel(const u16* __restrict__ qkv,
                                                   u16* __restrict__ ao) {
  __shared__ u16 Ks[64 * 128];       // K tile, rows chunk-swizzled: chunk ^= row&7
  __shared__ u16 Vt[128 * 88];       // V transposed [d][j], padded rows (176B)
  __shared__ u16 Pl[4][16 * 88];     // per-wave P tile [i][j], padded rows

  const int t = threadIdx.x;
  const int lane = t & 63, w = t >> 6;
  const int l15 = lane & 15, l4 = lane >> 4;
  const int qt = blockIdx.x, h = blockIdx.y, b = blockIdx.z;
  const int q0 = qt * 64, kvh = h >> 2;
  const int kcol = 2048 + kvh * 128, vcol = 2560 + kvh * 128;

  // Q fragments (MFMA A operand): row = l15, k = ch*32 + l4*8
  bf16x8 aq[4];
  {
    const size_t qbase = (size_t)(b*2048 + q0 + w*16 + l15) * 3072 + h*128 + l4*8;
#pragma unroll
    for (int ch = 0; ch < 4; ++ch)
      aq[ch] = *(const bf16x8*)&qkv[qbase + ch * 32];
  }

  f32x4 acc[8] = {};
  float mr[4] = {-INFINITY, -INFINITY, -INFINITY, -INFINITY};
  float sr[4] = {0.f, 0.f, 0.f, 0.f};

  const int krow_s = t >> 4;          // +16c -> row; LDS dest linear (byte=lane*16)
  const int kchk = t & 15;
  const int jp = t & 31, dbase = (t >> 5) << 4;

  const int nkv = qt + 1;
  const float scale = 0.08838834764831845f;   // 1/sqrt(128)

  for (int kb = 0; kb < nkv; ++kb) {
    __syncthreads();
    // ---- stage K via global_load_lds, source pre-swizzled for bank-free reads
#pragma unroll
    for (int c = 0; c < 4; ++c) {
      const int row = c * 16 + krow_s;
      const int gch = kchk ^ (row & 7);
      GLD16(&qkv[(size_t)(b*2048 + kb*64 + row) * 3072 + kcol + gch * 8],
            &Ks[row * 128 + kchk * 8]);
    }
    // ---- stage V transposed (reg-staged)
    {
      const u16* vp = &qkv[(size_t)(b*2048 + kb*64 + 2*jp) * 3072 + vcol + dbase];
      bf16x8 r0a = *(const bf16x8*)vp;
      bf16x8 r0b = *(const bf16x8*)(vp + 8);
      bf16x8 r1a = *(const bf16x8*)(vp + 3072);
      bf16x8 r1b = *(const bf16x8*)(vp + 3072 + 8);
#pragma unroll
      for (int i = 0; i < 8; ++i) {
        u32 p0 = (u32)(u16)r0a[i] | ((u32)(u16)r1a[i] << 16);
        u32 p1 = (u32)(u16)r0b[i] | ((u32)(u16)r1b[i] << 16);
        *(u32*)&Vt[(dbase + i) * 88 + 2*jp] = p0;
        *(u32*)&Vt[(dbase + 8 + i) * 88 + 2*jp] = p1;
      }
    }
    __syncthreads();

    // ---- S = Q K^T
    f32x4 s4[4] = {};
#pragma unroll
    for (int n = 0; n < 4; ++n) {
      const int krow = n * 16 + l15;
#pragma unroll
      for (int ch = 0; ch < 4; ++ch) {
        const int chk = (ch * 4 + l4) ^ (krow & 7);
        bf16x8 bk = *(const bf16x8*)&Ks[krow * 128 + chk * 8];
        s4[n] = MFMA16(aq[ch], bk, s4[n]);
      }
    }

    // ---- online softmax (rows i = l4*4+r, cols j = l15 + 16n; reduce over 16 lanes)
    float fac[4];
#pragma unroll
    for (int r = 0; r < 4; ++r) {
      const int i_row = q0 + w * 16 + l4 * 4 + r;
      float vmax = -INFINITY;
#pragma unroll
      for (int n = 0; n < 4; ++n) {
        float v = s4[n][r] * scale;
        const int j = kb * 64 + n * 16 + l15;
        if (j > i_row) v = -INFINITY;
        s4[n][r] = v;
        vmax = fmaxf(vmax, v);
      }
#pragma unroll
      for (int off = 8; off >= 1; off >>= 1)
        vmax = fmaxf(vmax, __shfl_xor(vmax, off, 64));
      const float mnew = fmaxf(mr[r], vmax);
      fac[r] = expf(mr[r] - mnew);
      float rsum = 0.f;
#pragma unroll
      for (int n = 0; n < 4; ++n) {
        float p = expf(s4[n][r] - mnew);
        s4[n][r] = p;
        rsum += p;
      }
#pragma unroll
      for (int off = 8; off >= 1; off >>= 1)
        rsum += __shfl_xor(rsum, off, 64);
      sr[r] = sr[r] * fac[r] + rsum;
      mr[r] = mnew;
    }
#pragma unroll
    for (int d0 = 0; d0 < 8; ++d0) {
      f32x4 a = acc[d0];
      a[0] *= fac[0]; a[1] *= fac[1]; a[2] *= fac[2]; a[3] *= fac[3];
      acc[d0] = a;
    }

    // ---- P (C-layout) -> LDS -> A-fragment layout
#pragma unroll
    for (int r = 0; r < 4; ++r)
#pragma unroll
      for (int n = 0; n < 4; ++n) {
        __hip_bfloat16 hp = __float2bfloat16(s4[n][r]);
        Pl[w][(l4 * 4 + r) * 88 + n * 16 + l15] = *(u16*)&hp;
      }
    asm volatile("s_waitcnt lgkmcnt(0)" ::: "memory");

    // ---- O += P V
    bf16x8 pa0 = *(const bf16x8*)&Pl[w][l15 * 88 + l4 * 8];
    bf16x8 pa1 = *(const bf16x8*)&Pl[w][l15 * 88 + 32 + l4 * 8];
#pragma unroll
    for (int d0 = 0; d0 < 8; ++d0) {
      bf16x8 bv0 = *(const bf16x8*)&Vt[(d0 * 16 + l15) * 88 + l4 * 8];
      bf16x8 bv1 = *(const bf16x8*)&Vt[(d0 * 16 + l15) * 88 + 32 + l4 * 8];
      acc[d0] = MFMA16(pa0, bv0, acc[d0]);
      acc[d0] = MFMA16(pa1, bv1, acc[d0]);
    }
  }

  // ---- epilogue: normalize, store bf16
  const size_t obase = (size_t)(b*2048 + q0 + w*16 + l4*4) * 2048 + h * 128 + l15;
#pragma unroll
  for (int r = 0; r < 4; ++r) {
    const float inv = 1.0f / sr[r];
#pragma unroll
    for (int d0 = 0; d0 < 8; ++d0) {
      __hip_bfloat16 hv = __float2bfloat16(acc[d0][r] * inv);
      ao[obase + (size_t)r * 2048 + d0 * 16] = *(u16*)&hv;
    }
  }
}

// ---------------------------------------------------------------- launch
extern "C" void kernel_launch(void* const* d_in, const int* in_sizes, int n_in,
                              void* d_out, int out_size, void* d_ws, size_t ws_size,
                              hipStream_t stream) {
  const float* x  = (const float*)d_in[0];
  // d_in[1] = causal mask (tril) — applied analytically
  const float* wq = (const float*)d_in[2];
  const float* wk = (const float*)d_in[3];
  const float* wv = (const float*)d_in[4];
  const float* wo = (const float*)d_in[5];
  float* out = (float*)d_out;

  // workspace layout (u16 elements)
  u16* xb   = (u16*)d_ws;                       // x bf16   [4096][2048]  (8.4M)
  u16* wqkv = xb + (size_t)8388608;             // W bf16   [3072][2048]  (6.3M)
  u16* qkv  = wqkv + (size_t)6291456;           // qkv      [4096][3072]  (12.6M)
  u16* ao   = xb;                               // attn out [4096][2048]  (reuse xb)
  u16* wob  = wqkv;                             // wo bf16  [2048][2048]  (reuse wqkv)

  cast_f32_bf16<<<8192, 256, 0, stream>>>(x,  xb,   2097152);
  cast_f32_bf16<<<4096, 256, 0, stream>>>(wq, wqkv, 1048576);
  cast_f32_bf16<<<1024, 256, 0, stream>>>(wk, wqkv + (size_t)4194304, 262144);
  cast_f32_bf16<<<1024, 256, 0, stream>>>(wv, wqkv + (size_t)5242880, 262144);

  gemm_bt<u16><<<dim3(24, 32), 256, 0, stream>>>(xb, wqkv, qkv, 4096, 3072, 2048);

  cast_f32_bf16<<<4096, 256, 0, stream>>>(wo, wob, 1048576);     // after GEMM1

  rmsrope_kernel<<<20480, 256, 0, stream>>>(qkv);

  attn_kernel<<<dim3(32, 16, 2), 256, 0, stream>>>(qkv, ao);

  gemm_bt<float><<<dim3(16, 32), 256, 0, stream>>>(ao, wob, out, 4096, 2048, 2048);
}

// Round 2
// 257.804 us; speedup vs baseline: 1.5614x; 1.5614x over previous
//
#include <hip/hip_runtime.h>
#include <hip/hip_bf16.h>

typedef unsigned short u16;
typedef unsigned int   u32;
typedef unsigned long long u64;
typedef __attribute__((ext_vector_type(8))) short bf16x8;
typedef __attribute__((ext_vector_type(4))) float f32x4;
typedef __attribute__((ext_vector_type(16))) float f32x16;

#define MFMA16(a,b,c) __builtin_amdgcn_mfma_f32_16x16x32_bf16((a),(b),(c),0,0,0)
#define MFMA32(a,b,c) __builtin_amdgcn_mfma_f32_32x32x16_bf16((a),(b),(c),0,0,0)

#define GLD16(gp, lp) __builtin_amdgcn_global_load_lds( \
    (const __attribute__((address_space(1))) void*)(gp), \
    (__attribute__((address_space(3))) void*)(lp), 16, 0, 0)

__device__ inline u32 pkbf(float a, float b) {
  __hip_bfloat16 ha = __float2bfloat16(a), hb = __float2bfloat16(b);
  return (u32)(*(u16*)&ha) | ((u32)(*(u16*)&hb) << 16);
}

// ---------------------------------------------------------------- cast f32->bf16
__global__ __launch_bounds__(256) void cast_f32_bf16(const float* __restrict__ src,
                                                     u16* __restrict__ dst, int n4) {
  int i = blockIdx.x * 256 + threadIdx.x;
  if (i >= n4) return;
  float4 v = reinterpret_cast<const float4*>(src)[i];
  __hip_bfloat16 h0 = __float2bfloat16(v.x);
  __hip_bfloat16 h1 = __float2bfloat16(v.y);
  __hip_bfloat16 h2 = __float2bfloat16(v.z);
  __hip_bfloat16 h3 = __float2bfloat16(v.w);
  u32 lo = (u32)(*(u16*)&h0) | ((u32)(*(u16*)&h1) << 16);
  u32 hi = (u32)(*(u16*)&h2) | ((u32)(*(u16*)&h3) << 16);
  uint2 pk; pk.x = lo; pk.y = hi;
  reinterpret_cast<uint2*>(dst)[i] = pk;
}

// ---------------------------------------------------------------- GEMM C = A * B^T
__device__ inline void cstore(u16* C, size_t i, float v) {
  __hip_bfloat16 h = __float2bfloat16(v); C[i] = *(u16*)&h;
}
__device__ inline void cstore(float* C, size_t i, float v) { C[i] = v; }

template<typename OutT>
__global__ __launch_bounds__(256) void gemm_bt(const u16* __restrict__ A,
                                               const u16* __restrict__ B,
                                               OutT* __restrict__ C,
                                               int M, int N, int K) {
  __shared__ u16 As[128 * 32];
  __shared__ u16 Bs[128 * 32];
  const int t = threadIdx.x;
  const int lane = t & 63, wid = t >> 6;
  const int l15 = lane & 15, l4 = lane >> 4;
  const int wr = wid >> 1, wc = wid & 1;
  const int m0 = blockIdx.y * 128, n0 = blockIdx.x * 128;

  const int srow = t >> 2, scol = (t & 3) << 3;
  const u16* Ag = A + (size_t)(m0 + srow) * K + scol;
  const u16* Bg = B + (size_t)(n0 + srow) * K + scol;
  u16* As_d  = &As[srow * 32 + scol];
  u16* As_d2 = &As[(srow + 64) * 32 + scol];
  u16* Bs_d  = &Bs[srow * 32 + scol];
  u16* Bs_d2 = &Bs[(srow + 64) * 32 + scol];

  const int fra = wr * 64 + l15;
  const int frb = wc * 64 + l15;
  const int fk  = l4 << 3;

  f32x4 acc[4][4] = {};
  for (int k0 = 0; k0 < K; k0 += 32) {
    __syncthreads();
    GLD16(Ag + k0,                 As_d);
    GLD16(Ag + (size_t)64*K + k0,  As_d2);
    GLD16(Bg + k0,                 Bs_d);
    GLD16(Bg + (size_t)64*K + k0,  Bs_d2);
    __syncthreads();
    bf16x8 af[4], bfr[4];
#pragma unroll
    for (int m = 0; m < 4; ++m) af[m]  = *(const bf16x8*)&As[(fra + m*16)*32 + fk];
#pragma unroll
    for (int n = 0; n < 4; ++n) bfr[n] = *(const bf16x8*)&Bs[(frb + n*16)*32 + fk];
#pragma unroll
    for (int m = 0; m < 4; ++m)
#pragma unroll
      for (int n = 0; n < 4; ++n)
        acc[m][n] = MFMA16(af[m], bfr[n], acc[m][n]);
  }
  const int crow = m0 + wr * 64 + (l4 << 2);
  const int ccol = n0 + wc * 64 + l15;
#pragma unroll
  for (int m = 0; m < 4; ++m)
#pragma unroll
    for (int n = 0; n < 4; ++n)
#pragma unroll
      for (int r = 0; r < 4; ++r)
        cstore(C, (size_t)(crow + m*16 + r) * N + (ccol + n*16), acc[m][n][r]);
}

// ---------------------------------------------------------------- RMSNorm + RoPE
__global__ __launch_bounds__(256) void rmsrope_kernel(u16* __restrict__ qkv) {
  const int t = threadIdx.x;
  const int lane = t & 63;
  const int gw = blockIdx.x * 4 + (t >> 6);
  const int row = gw / 20;
  const int hd = gw - row * 20;
  const int col = (hd < 16) ? hd * 128 : 2048 + (hd - 16) * 128;
  const size_t base = (size_t)row * 3072 + col;
  float x1 = __bfloat162float(*(const __hip_bfloat16*)&qkv[base + lane]);
  float x2 = __bfloat162float(*(const __hip_bfloat16*)&qkv[base + 64 + lane]);
  float ss = x1 * x1 + x2 * x2;
#pragma unroll
  for (int off = 32; off >= 1; off >>= 1) ss += __shfl_xor(ss, off, 64);
  const float sc = rsqrtf(ss * (1.0f / 128.0f) + 1e-6f);
  const int pos = row & 2047;
  const float inv_freq = exp2f(-(float)lane * (13.287712379549449f / 64.0f));
  float sn, cs;
  sincosf((float)pos * inv_freq, &sn, &cs);
  const float a = x1 * sc, b2 = x2 * sc;
  __hip_bfloat16 o1 = __float2bfloat16(a * cs - b2 * sn);
  __hip_bfloat16 o2 = __float2bfloat16(a * sn + b2 * cs);
  qkv[base + lane] = *(u16*)&o1;
  qkv[base + 64 + lane] = *(u16*)&o2;
}

// ---------------------------------------------------------------- flash attention
// 4 waves x 32 q-rows = 128 q-rows/block; KVBLK=64; 32x32x16 MFMA, swapped
// QK^T (S^T: col=q=lane&31) and PV as O^T = V^T * P (col=q). In-register
// softmax (exp2 domain, defer-max), P redistributed via shfl_xor(32).
// K/V double-buffered in LDS, chunk-XOR swizzle (^ row&7), 1 barrier/iter.
__global__ __launch_bounds__(256, 2) void attn_kernel(const u16* __restrict__ qkv,
                                                      u16* __restrict__ ao) {
  __shared__ u16 Ks[2][64 * 128];   // [k][d], d-chunks(8 u16) XORed by k&7
  __shared__ u16 Vt[2][128 * 64];   // [d][k], k-chunks(8 u16) XORed by d&7

  const int t = threadIdx.x;
  const int lane = t & 63, w = t >> 6;
  const int l31 = lane & 31, hi = lane >> 5;

  const int bid = blockIdx.x;
  const int pairh = bid >> 8, rest = bid & 255;
  const int h = rest & 15, b = (rest >> 4) & 1;
  const int q8 = rest >> 5;
  const int qt = pairh ? (15 - q8) : q8;      // anti-correlated work pairing
  const int q0 = qt * 128;
  const int kvh = h >> 2;
  const int kcol = 2048 + kvh * 128, vcol = 2560 + kvh * 128;
  const int nkv = 2 * (qt + 1);
  const int qrow = q0 + w * 32 + l31;         // this lane's q column

  // Q fragments (B operand): col=q, kk=d = st*16 + hi*8 + i
  bf16x8 qf[8];
  {
    const u16* qp = qkv + (size_t)(b * 2048 + qrow) * 3072 + h * 128 + hi * 8;
#pragma unroll
    for (int st = 0; st < 8; ++st) qf[st] = *(const bf16x8*)(qp + st * 16);
  }

  f32x16 o[4];
#pragma unroll
  for (int dt = 0; dt < 4; ++dt)
#pragma unroll
    for (int i = 0; i < 16; ++i) o[dt][i] = 0.f;
  float m2 = -INFINITY, l = 0.f;

  const int jv = t & 15, dc = t >> 4;         // V staging: rows 4jv..+3, d=dc*8..+7
  const int krow_s = t >> 4, kchk = t & 15;   // K staging

#define STAGE_K(kb_, buf_) do {                                               \
    const size_t rb_ = (size_t)(b * 2048 + (kb_) * 64);                       \
    _Pragma("unroll")                                                         \
    for (int j_ = 0; j_ < 4; ++j_) {                                          \
      const int row_ = j_ * 16 + krow_s;                                      \
      GLD16(qkv + (rb_ + row_) * 3072 + kcol + ((kchk ^ (row_ & 7)) << 3),    \
            &Ks[buf_][(j_ * 256 + t) << 3]);                                  \
    } } while (0)

#define LOAD_V(kb_, vr_) do {                                                 \
    const u16* vp_ = qkv + (size_t)(b * 2048 + (kb_) * 64 + 4 * jv) * 3072    \
                     + vcol + dc * 8;                                         \
    vr_[0] = *(const bf16x8*)vp_;                                             \
    vr_[1] = *(const bf16x8*)(vp_ + 3072);                                    \
    vr_[2] = *(const bf16x8*)(vp_ + 6144);                                    \
    vr_[3] = *(const bf16x8*)(vp_ + 9216);                                    \
  } while (0)

#define WRITE_V(vr_, buf_) do {                                               \
    _Pragma("unroll")                                                         \
    for (int i_ = 0; i_ < 8; ++i_) {                                          \
      const int d_ = dc * 8 + i_;                                             \
      u64 val_ = (u64)(u16)vr_[0][i_] | ((u64)(u16)vr_[1][i_] << 16)          \
               | ((u64)(u16)vr_[2][i_] << 32) | ((u64)(u16)vr_[3][i_] << 48); \
      *(u64*)&Vt[buf_][d_ * 64 + (((jv >> 1) ^ i_) << 3) + ((jv & 1) << 2)]   \
          = val_;                                                             \
    } } while (0)

  // prologue: stage tile 0 into buffer 0
  {
    bf16x8 v0[4];
    LOAD_V(0, v0);
    STAGE_K(0, 0);
    WRITE_V(v0, 0);
  }
  __syncthreads();

  const float sc2 = 0.08838834764831845f * 1.44269504088896340f;  // scale*log2e

  for (int kb = 0; kb < nkv; ++kb) {
    const int cur = kb & 1, nxt = cur ^ 1;
    const bool have_next = (kb + 1 < nkv);
    bf16x8 vnext[4];
    if (have_next) {
      LOAD_V(kb + 1, vnext);
      if (nxt) STAGE_K(kb + 1, 1); else STAGE_K(kb + 1, 0);
    }
    const bool active = (kb * 64 <= q0 + w * 32 + 31);

    bf16x8 pa[4];
    if (active) {
      // ---- S^T = K Q^T  (rows k, cols q)
      f32x16 s0, s1;
#pragma unroll
      for (int i = 0; i < 16; ++i) { s0[i] = 0.f; s1[i] = 0.f; }
      const int kbase  = l31 * 128;
      const int kbase2 = (32 + l31) * 128;
      const int ksw = l31 & 7;
#pragma unroll
      for (int st = 0; st < 8; ++st) {
        const int c = ((2 * st + hi) ^ ksw) << 3;
        bf16x8 ka  = *(const bf16x8*)&Ks[cur][kbase + c];
        bf16x8 kb2 = *(const bf16x8*)&Ks[cur][kbase2 + c];
        s0 = MFMA32(ka,  qf[st], s0);
        s1 = MFMA32(kb2, qf[st], s1);
      }
      // ---- mask + scale (exp2 domain), row max
      float pm = -INFINITY;
      const bool nomask = (kb * 64 + 63) <= (q0 + w * 32);
      if (nomask) {
#pragma unroll
        for (int i = 0; i < 16; ++i) {
          s0[i] *= sc2; s1[i] *= sc2;
          pm = fmaxf(pm, fmaxf(s0[i], s1[i]));
        }
      } else {
#pragma unroll
        for (int i = 0; i < 16; ++i) {
          const int kr = kb * 64 + (i & 3) + 8 * (i >> 2) + 4 * hi;
          s0[i] = (kr <= qrow)      ? s0[i] * sc2 : -INFINITY;
          s1[i] = (kr + 32 <= qrow) ? s1[i] * sc2 : -INFINITY;
          pm = fmaxf(pm, fmaxf(s0[i], s1[i]));
        }
      }
      pm = fmaxf(pm, __shfl_xor(pm, 32));
      // ---- defer-max rescale
      if (!__all(pm <= m2 + 8.f)) {
        const float m2n = fmaxf(m2, pm);
        const float fc = exp2f(m2 - m2n);
        m2 = m2n; l *= fc;
#pragma unroll
        for (int dt = 0; dt < 4; ++dt)
#pragma unroll
          for (int i = 0; i < 16; ++i) o[dt][i] *= fc;
      }
      // ---- P = exp2(z - m2), row sum
      float sum = 0.f;
#pragma unroll
      for (int i = 0; i < 16; ++i) { s0[i] = exp2f(s0[i] - m2); sum += s0[i]; }
#pragma unroll
      for (int i = 0; i < 16; ++i) { s1[i] = exp2f(s1[i] - m2); sum += s1[i]; }
      sum += __shfl_xor(sum, 32);
      l += sum;
      // ---- pack P to bf16 pairs, redistribute across hi-halves
      u32 W[16], Wx[16];
#pragma unroll
      for (int i = 0; i < 8; ++i) W[i]     = pkbf(s0[2*i], s0[2*i+1]);
#pragma unroll
      for (int i = 0; i < 8; ++i) W[8 + i] = pkbf(s1[2*i], s1[2*i+1]);
#pragma unroll
      for (int i = 0; i < 16; ++i) Wx[i] = (u32)__shfl_xor((int)W[i], 32);
      union FR { u32 wd[4]; bf16x8 v; };
#pragma unroll
      for (int kt = 0; kt < 2; ++kt) {
        const int bse = kt * 8;
        FR fa, fb;
        fa.wd[0] = hi ? Wx[bse+2] : W[bse+0];
        fa.wd[1] = hi ? Wx[bse+3] : W[bse+1];
        fa.wd[2] = hi ? W[bse+2]  : Wx[bse+0];
        fa.wd[3] = hi ? W[bse+3]  : Wx[bse+1];
        fb.wd[0] = hi ? Wx[bse+6] : W[bse+4];
        fb.wd[1] = hi ? Wx[bse+7] : W[bse+5];
        fb.wd[2] = hi ? W[bse+6]  : Wx[bse+4];
        fb.wd[3] = hi ? W[bse+7]  : Wx[bse+5];
        pa[2*kt]     = fa.v;
        pa[2*kt + 1] = fb.v;
      }
    }
    // write next V tile (after softmax: global-load latency hidden)
    if (have_next) { if (nxt) WRITE_V(vnext, 1); else WRITE_V(vnext, 0); }
    if (active) {
      // ---- O^T += V^T P  (rows d, cols q)
#pragma unroll
      for (int dt = 0; dt < 4; ++dt) {
        const int vrow = (dt * 32 + l31) * 64;
        const int dsw = l31 & 7;
#pragma unroll
        for (int ks = 0; ks < 4; ++ks) {
          bf16x8 va = *(const bf16x8*)&Vt[cur][vrow + (((2 * ks + hi) ^ dsw) << 3)];
          o[dt] = MFMA32(va, pa[ks], o[dt]);
        }
      }
    }
    __syncthreads();
  }

  // ---- epilogue: normalize, store O (rows d = crow, col q lane-local)
  const float inv = 1.f / l;
  const size_t ob = (size_t)(b * 2048 + qrow) * 2048 + h * 128 + 4 * hi;
#pragma unroll
  for (int dt = 0; dt < 4; ++dt)
#pragma unroll
    for (int m = 0; m < 4; ++m) {
      u64 val = 0;
#pragma unroll
      for (int r = 0; r < 4; ++r) {
        __hip_bfloat16 hb = __float2bfloat16(o[dt][4*m + r] * inv);
        val |= (u64)(*(u16*)&hb) << (16 * r);
      }
      *(u64*)&ao[ob + dt * 32 + 8 * m] = val;
    }
#undef STAGE_K
#undef LOAD_V
#undef WRITE_V
}

// ---------------------------------------------------------------- launch
extern "C" void kernel_launch(void* const* d_in, const int* in_sizes, int n_in,
                              void* d_out, int out_size, void* d_ws, size_t ws_size,
                              hipStream_t stream) {
  const float* x  = (const float*)d_in[0];
  const float* wq = (const float*)d_in[2];
  const float* wk = (const float*)d_in[3];
  const float* wv = (const float*)d_in[4];
  const float* wo = (const float*)d_in[5];
  float* out = (float*)d_out;

  u16* xb   = (u16*)d_ws;                       // x bf16   [4096][2048]
  u16* wqkv = xb + (size_t)8388608;             // W bf16   [3072][2048]
  u16* qkv  = wqkv + (size_t)6291456;           // qkv      [4096][3072]
  u16* ao   = xb;                               // attn out [4096][2048] (reuse xb)
  u16* wob  = wqkv;                             // wo bf16  [2048][2048] (reuse)

  cast_f32_bf16<<<8192, 256, 0, stream>>>(x,  xb,   2097152);
  cast_f32_bf16<<<4096, 256, 0, stream>>>(wq, wqkv, 1048576);
  cast_f32_bf16<<<1024, 256, 0, stream>>>(wk, wqkv + (size_t)4194304, 262144);
  cast_f32_bf16<<<1024, 256, 0, stream>>>(wv, wqkv + (size_t)5242880, 262144);

  gemm_bt<u16><<<dim3(24, 32), 256, 0, stream>>>(xb, wqkv, qkv, 4096, 3072, 2048);

  cast_f32_bf16<<<4096, 256, 0, stream>>>(wo, wob, 1048576);

  rmsrope_kernel<<<20480, 256, 0, stream>>>(qkv);

  attn_kernel<<<512, 256, 0, stream>>>(qkv, ao);

  gemm_bt<float><<<dim3(16, 32), 256, 0, stream>>>(ao, wob, out, 4096, 2048, 2048);
}